// Round 1
// baseline (359.162 us; speedup 1.0000x reference)
//
#include <hip/hip_runtime.h>
#include <hip/hip_bf16.h>
#include <stdint.h>

// TrellisQuantizer: out[i,j,:] = tlut[(h>>5)&1023] * signs, h=(e+1)*e, e=encoded[i,j]
// Memory-bound: 128 MiB read (encoded) + 512 MiB write (fp32 out) -> ~105 us roofline.

constexpr int TLUT_ENTRIES = 1024;   // 2^10 entries of float2
constexpr int BLOCK = 256;

__global__ __launch_bounds__(BLOCK) void trellis_dequant_kernel(
    const float2* __restrict__ tlut,   // [1024] float2
    const int2*   __restrict__ enc,    // encoded viewed as pairs
    float4*       __restrict__ out,    // output viewed as float4 (2 codes -> 4 floats)
    int n2)                            // number of int2 elements
{
    __shared__ float2 slut[TLUT_ENTRIES];
    for (int j = threadIdx.x; j < TLUT_ENTRIES; j += BLOCK)
        slut[j] = tlut[j];
    __syncthreads();

    const int stride = gridDim.x * BLOCK;
    for (int i = blockIdx.x * BLOCK + threadIdx.x; i < n2; i += stride) {
        int2 e = enc[i];
        uint32_t e0 = (uint32_t)e.x;
        uint32_t e1 = (uint32_t)e.y;
        uint32_t h0 = (e0 + 1u) * e0;
        uint32_t h1 = (e1 + 1u) * e1;

        float2 t0 = slut[(h0 >> 5) & 1023u];
        float2 t1 = slut[(h1 >> 5) & 1023u];

        // sflp0 = bit15 of h -> sign bit; sflp1 = bit13 of h -> sign bit.
        // XOR of the sign bit is bit-exact vs multiply by +/-1.0f.
        uint32_t s00 = (h0 & 0x8000u) << 16;
        uint32_t s01 = (h0 & 0x2000u) << 18;
        uint32_t s10 = (h1 & 0x8000u) << 16;
        uint32_t s11 = (h1 & 0x2000u) << 18;

        float4 o;
        o.x = __uint_as_float(__float_as_uint(t0.x) ^ s00);
        o.y = __uint_as_float(__float_as_uint(t0.y) ^ s01);
        o.z = __uint_as_float(__float_as_uint(t1.x) ^ s10);
        o.w = __uint_as_float(__float_as_uint(t1.y) ^ s11);
        out[i] = o;
    }
}

extern "C" void kernel_launch(void* const* d_in, const int* in_sizes, int n_in,
                              void* d_out, int out_size, void* d_ws, size_t ws_size,
                              hipStream_t stream) {
    const float2* tlut = (const float2*)d_in[0];   // [1024,2] fp32
    const int2*   enc  = (const int2*)d_in[1];     // [16384,2048] int32, viewed as int2
    float4*       out  = (float4*)d_out;           // [16384,2048,2] fp32, viewed as float4

    const int n_codes = in_sizes[1];               // 16384*2048 = 33,554,432
    const int n2 = n_codes / 2;                    // int2 elements = 16,777,216

    const int blocks = 8192;                       // grid-stride, 32 blocks/CU worth of work
    trellis_dequant_kernel<<<blocks, BLOCK, 0, stream>>>(tlut, enc, out, n2);
}

// Round 2
// 356.057 us; speedup vs baseline: 1.0087x; 1.0087x over previous
//
#include <hip/hip_runtime.h>
#include <hip/hip_bf16.h>
#include <stdint.h>

// TrellisQuantizer: out[i,j,:] = tlut[(h>>5)&1023] ^ sign(h bits 15/13), h=(e+1)*e
// Memory-bound: 134 MB read (encoded int32) + 268 MB write (fp32 out)
// -> ~63 us floor at 6.35 TB/s measured. Bit-exact sign flip via XOR of sign bit.

constexpr int TLUT_ENTRIES = 1024;   // 2^10 entries of float2 (8 KiB, LDS-resident)
constexpr int BLOCK = 256;

typedef float f32x4 __attribute__((ext_vector_type(4)));

__global__ __launch_bounds__(BLOCK) void trellis_dequant_kernel(
    const float2*   __restrict__ tlut,   // [1024] float2
    const uint64_t* __restrict__ enc,    // encoded viewed as packed pairs of int32
    f32x4*          __restrict__ out,    // output viewed as float4 (2 codes -> 4 floats)
    int n2)                              // number of uint64 (code-pair) elements
{
    __shared__ float2 slut[TLUT_ENTRIES];
    for (int j = threadIdx.x; j < TLUT_ENTRIES; j += BLOCK)
        slut[j] = tlut[j];
    __syncthreads();

    const int stride = gridDim.x * BLOCK;
    int i = blockIdx.x * BLOCK + threadIdx.x;
    #pragma unroll 2
    for (; i < n2; i += stride) {
        // Nontemporal: streamed once, never re-read -> don't occupy L2.
        uint64_t e2 = __builtin_nontemporal_load(&enc[i]);
        uint32_t e0 = (uint32_t)e2;
        uint32_t e1 = (uint32_t)(e2 >> 32);
        uint32_t h0 = (e0 + 1u) * e0;
        uint32_t h1 = (e1 + 1u) * e1;

        float2 t0 = slut[(h0 >> 5) & 1023u];
        float2 t1 = slut[(h1 >> 5) & 1023u];

        // sflp0 = bit15 of h -> sign bit; sflp1 = bit13 of h -> sign bit.
        uint32_t s00 = (h0 & 0x8000u) << 16;
        uint32_t s01 = (h0 & 0x2000u) << 18;
        uint32_t s10 = (h1 & 0x8000u) << 16;
        uint32_t s11 = (h1 & 0x2000u) << 18;

        f32x4 o;
        o.x = __uint_as_float(__float_as_uint(t0.x) ^ s00);
        o.y = __uint_as_float(__float_as_uint(t0.y) ^ s01);
        o.z = __uint_as_float(__float_as_uint(t1.x) ^ s10);
        o.w = __uint_as_float(__float_as_uint(t1.y) ^ s11);
        __builtin_nontemporal_store(o, &out[i]);
    }
}

extern "C" void kernel_launch(void* const* d_in, const int* in_sizes, int n_in,
                              void* d_out, int out_size, void* d_ws, size_t ws_size,
                              hipStream_t stream) {
    const float2*   tlut = (const float2*)d_in[0];     // [1024,2] fp32
    const uint64_t* enc  = (const uint64_t*)d_in[1];   // [16384,2048] int32, pair-packed
    f32x4*          out  = (f32x4*)d_out;              // [16384,2048,2] fp32 as float4

    const int n_codes = in_sizes[1];                   // 16384*2048 = 33,554,432
    const int n2 = n_codes / 2;                        // 16,777,216 pairs

    const int blocks = 8192;                           // 2M threads -> exactly 8 iters each
    trellis_dequant_kernel<<<blocks, BLOCK, 0, stream>>>(tlut, enc, out, n2);
}